// Round 10
// baseline (170.111 us; speedup 1.0000x reference)
//
#include <hip/hip_runtime.h>

#define BB 2
#define HH 1024
#define WW 1024
#define MU 5

// fused-pass tile geometry
#define TH 32
#define TW 64
#define SH (TH + 2 * MU)   // 42 staged rows
#define SCW 80             // staged cols (8-col halo each side)
#define SMS 83             // em LDS row stride (odd -> conflict-free)
#define SVS 81             // V-result LDS row stride (odd -> conflict-free)

__device__ __forceinline__ float fast_rcp(float x) { return __builtin_amdgcn_rcpf(x); }
__device__ __forceinline__ float fast_rsq(float x) { return __builtin_amdgcn_rsqf(x); }

// ---------------------------------------------------------------------------
// Kernel 1: Sobel + init tangent + raw mag + LAST-BLOCK global-max reduce.
// Each block: write block_max[bid], device fence, atomicAdd ticket; ticket
// 1023 (all maxes visible) reduces 1024 -> gmax. No extra dispatch, no
// dispatch-order assumption (no spin-wait), device-scope atomics (G16-safe).
// ---------------------------------------------------------------------------
#define SR 8
__global__ __launch_bounds__(256) void sobel_init(
    const float* __restrict__ x,
    float2* __restrict__ tf,          // (B,H,W) float2
    float* __restrict__ mag,          // (B,H,W) raw
    float* __restrict__ block_max,    // 1024
    unsigned int* __restrict__ counter,
    float* __restrict__ gmax)
{
    __shared__ float xs[SR + 2][264];
    const int t = threadIdx.x;
    const int w0 = blockIdx.x * 256;
    const int h0 = blockIdx.y * SR;
    const int b = blockIdx.z;
    const int bid = (blockIdx.z * 128 + blockIdx.y) * 4 + blockIdx.x;
    const size_t plane = (size_t)HH * WW;
    const float* xb = x + (size_t)b * plane;

    for (int i = t; i < (SR + 2) * 66; i += 256) {
        int r = i / 66, c4 = i % 66;
        int g = h0 - 1 + r;
        int gw = w0 - 4 + 4 * c4;
        float4 v = make_float4(0.f, 0.f, 0.f, 0.f);
        if (g >= 0 && g < HH && gw >= 0 && gw < WW)
            v = *(const float4*)(xb + (size_t)g * WW + gw);
        *(float4*)&xs[r][4 * c4] = v;
    }
    __syncthreads();

    float lmax = 0.f;
    const int c = 4 + t;
    #pragma unroll
    for (int k = 0; k < SR; ++k) {
        const float* rT = xs[k], * rM = xs[k + 1], * rB = xs[k + 2];
        float tl = rT[c - 1], tc = rT[c], tr = rT[c + 1];
        float ml = rM[c - 1],             mr = rM[c + 1];
        float bl = rB[c - 1], bc = rB[c], br = rB[c + 1];
        float s0 = (bl - tl) + 2.f * (bc - tc) + (br - tr);   // k
        float s1 = (tr - tl) + 2.f * (mr - ml) + (br - bl);   // k^T
        float m = sqrtf(fmaf(s0, s0, s1 * s1));
        float inv = (m == 0.f) ? 1.f : fast_rcp(m);
        size_t gi = (size_t)(h0 + k) * WW + (w0 + t);
        mag[(size_t)b * plane + gi] = m;
        tf[(size_t)b * plane + gi] = make_float2(-s1 * inv, s0 * inv);
        lmax = fmaxf(lmax, m);
    }

    #pragma unroll
    for (int off = 32; off; off >>= 1) lmax = fmaxf(lmax, __shfl_down(lmax, off, 64));
    __shared__ float smax[4];
    __shared__ int lastflag;
    if ((t & 63) == 0) smax[t >> 6] = lmax;
    __syncthreads();
    if (t == 0) {
        block_max[bid] = fmaxf(fmaxf(smax[0], smax[1]), fmaxf(smax[2], smax[3]));
        __threadfence();                               // publish before ticket
        unsigned int old = atomicAdd(counter, 1u);
        lastflag = (old == 1023u);
    }
    __syncthreads();
    if (lastflag) {
        __threadfence();                               // acquire all block_max
        float m = fmaxf(fmaxf(block_max[t], block_max[t + 256]),
                        fmaxf(block_max[t + 512], block_max[t + 768]));
        #pragma unroll
        for (int off = 32; off; off >>= 1) m = fmaxf(m, __shfl_down(m, off, 64));
        if ((t & 63) == 0) smax[t >> 6] = m;
        __syncthreads();
        if (t == 0) gmax[0] = fmaxf(fmaxf(smax[0], smax[1]), fmaxf(smax[2], smax[3]));
    }
}

// ---------------------------------------------------------------------------
// Kernel 2: FUSED V+H ETF pass — 3 barriers (was 5).
//   stage (tang + em=exp(-2*mag/max), from RAW mag)  -> sync
//   V: 21-value register windows (240 thr)           -> sync (alias protect)
//   V writes normalized results into aliased region  -> sync
//   H: 18-value register window, computes and writes DIRECTLY to global.
// Weight identity: (tanh(my-mx)+1)/2 == 1/(1 + em_y/em_x).
// LDS 40824 B -> 4 blocks/CU, __launch_bounds__(256,4).
// OOB staging: tang=0, em=1 (exact reference zero-pad; normalize(0)=0).
// ---------------------------------------------------------------------------
template <int PLANAR_OUT>
__global__ __launch_bounds__(256, 4) void etf_vh(
    const float2* __restrict__ tin,  // (B,H,W) float2
    float* __restrict__ tout,        // float2 interleaved, or planar (B,2,H,W)
    const float* __restrict__ mag,   // (B,H,W) RAW
    const float* __restrict__ gmax)
{
    __shared__ float lds[SH * SCW * 2 + SH * SMS];   // 40824 B
    float* st  = lds;                 // staged tang (float2/px, row stride 160)
    float* sm  = lds + SH * SCW * 2;  // staged em, row stride SMS
    float* sv0 = lds;                 // V results plane 0 (aliases st)
    float* sv1 = lds + TH * SVS;      // V results plane 1

    const int t = threadIdx.x;
    const int w0 = blockIdx.x * TW;
    const int h0 = blockIdx.y * TH;
    const int b = blockIdx.z;
    const size_t plane = (size_t)HH * WW;
    const float2* tb = tin + (size_t)b * plane;
    const float*  mb = mag + (size_t)b * plane;
    const float s2 = 2.f * fast_rcp(gmax[0]);

    // ---- stage: tang 42x40 float4 (2px) chunks; em 42x20 float4 (4px) + exp
    for (int i = t; i < SH * 40 + SH * 20; i += 256) {
        if (i < SH * 40) {
            int r = i / 40, c4 = i % 40;
            int g = h0 - MU + r;
            int gw = w0 - 8 + 2 * c4;
            float4 v = make_float4(0.f, 0.f, 0.f, 0.f);
            if (g >= 0 && g < HH && gw >= 0 && gw < WW)
                v = *(const float4*)(tb + (size_t)g * WW + gw);
            *(float4*)&st[r * (SCW * 2) + 4 * c4] = v;
        } else {
            int j = i - SH * 40;
            int r = j / 20, c4 = j % 20;
            int g = h0 - MU + r;
            int gw = w0 - 8 + 4 * c4;
            float4 v = make_float4(0.f, 0.f, 0.f, 0.f);   // mag=0 -> em=1
            if (g >= 0 && g < HH && gw >= 0 && gw < WW)
                v = *(const float4*)(mb + (size_t)g * WW + gw);
            float* dst = &sm[r * SMS + 4 * c4];
            dst[0] = __expf(-s2 * v.x);
            dst[1] = __expf(-s2 * v.y);
            dst[2] = __expf(-s2 * v.z);
            dst[3] = __expf(-s2 * v.w);
        }
    }
    __syncthreads();                                  // s1

    // ---- shared register window (V uses 21; H reuses first 18)
    float r0a[21], r1a[21], rea[21];

    // ---- V phase: 240 threads = 80 cols x 3 row-strips {11,11,10}
    const int vc = t % 80;
    const int strip = t / 80;
    const int vrow = strip * 11;
    const int Rv = (strip == 2) ? 10 : 11;
    if (t < 240) {
        #pragma unroll
        for (int j = 0; j < 21; ++j) {
            if (j < Rv + 10) {
                float2 v = *(const float2*)&st[((vrow + j) * SCW + vc) * 2];
                r0a[j] = v.x; r1a[j] = v.y;
                rea[j] = sm[(vrow + j) * SMS + vc];
            }
        }
    }
    __syncthreads();                                  // s2: st reads done

    if (t < 240) {
        #pragma unroll
        for (int i = 0; i < 11; ++i) {
            if (i < Rv) {
                float tx0 = r0a[i + 5], tx1 = r1a[i + 5];
                float remx = fast_rcp(rea[i + 5]);
                float a0 = 0.f, a1 = 0.f;
                #pragma unroll
                for (int d = 0; d <= 2 * MU; ++d) {
                    float s = fast_rcp(fmaf(rea[i + d], remx, 1.f));
                    float w = s * fmaf(tx0, r0a[i + d], tx1 * r1a[i + d]);
                    a0 = fmaf(r0a[i + d], w, a0);
                    a1 = fmaf(r1a[i + d], w, a1);
                }
                float n2 = fmaf(a0, a0, a1 * a1);
                float inv = (n2 == 0.f) ? 1.f : fast_rsq(n2);
                sv0[(vrow + i) * SVS + vc] = a0 * inv;
                sv1[(vrow + i) * SVS + vc] = a1 * inv;
            }
        }
    }
    __syncthreads();                                  // s3: sv complete

    // ---- H phase: r = t&31 (row), cg = t>>5 (8-col group); direct global write
    const int r  = t & 31;
    const int cg = t >> 5;
    const int cb = 8 + cg * 8;
    #pragma unroll
    for (int j = 0; j < 18; ++j) {                    // staged cols 3..76
        r0a[j] = sv0[r * SVS + cb - MU + j];
        r1a[j] = sv1[r * SVS + cb - MU + j];
        rea[j] = sm[(r + MU) * SMS + cb - MU + j];
    }
    #pragma unroll
    for (int k = 0; k < 8; ++k) {
        float tx0 = r0a[k + 5], tx1 = r1a[k + 5];
        float remx = fast_rcp(rea[k + 5]);
        float a0 = 0.f, a1 = 0.f;
        #pragma unroll
        for (int d = 0; d <= 2 * MU; ++d) {
            float s = fast_rcp(fmaf(rea[k + d], remx, 1.f));
            float w = s * fmaf(tx0, r0a[k + d], tx1 * r1a[k + d]);
            a0 = fmaf(r0a[k + d], w, a0);
            a1 = fmaf(r1a[k + d], w, a1);
        }
        float n2 = fmaf(a0, a0, a1 * a1);
        float inv = (n2 == 0.f) ? 1.f : fast_rsq(n2);
        size_t gi = (size_t)(h0 + r) * WW + (w0 + cg * 8 + k);
        if (PLANAR_OUT) {
            tout[(size_t)(2 * b)     * plane + gi] = a0 * inv;
            tout[(size_t)(2 * b + 1) * plane + gi] = a1 * inv;
        } else {
            ((float2*)tout)[(size_t)b * plane + gi] = make_float2(a0 * inv, a1 * inv);
        }
    }
}

extern "C" void kernel_launch(void* const* d_in, const int* in_sizes, int n_in,
                              void* d_out, int out_size, void* d_ws, size_t ws_size,
                              hipStream_t stream)
{
    const float* x = (const float*)d_in[0];   // (2,1,1024,1024) fp32
    char* ws = (char*)d_ws;
    const size_t plane = (size_t)HH * WW;

    float2* tfA = (float2*)ws;                                          // 16 MB
    float2* tfB = (float2*)(ws + sizeof(float) * BB * 2 * plane);       // 16 MB
    float* mag  = (float*)(ws + sizeof(float) * BB * 4 * plane);        // 8 MB raw
    float* gmax = (float*)(ws + sizeof(float) * BB * 5 * plane);        // 4 B
    float* block_max = gmax + 16;                                       // 1024 floats
    unsigned int* counter = (unsigned int*)(block_max + 1024);          // 4 B

    hipMemsetAsync(counter, 0, sizeof(unsigned int), stream);

    sobel_init<<<dim3(4, 128, BB), 256, 0, stream>>>(x, tfA, mag, block_max,
                                                     counter, gmax);

    dim3 g(WW / TW, HH / TH, BB);
    etf_vh<0><<<g, 256, 0, stream>>>(tfA, (float*)tfB, mag, gmax);
    etf_vh<0><<<g, 256, 0, stream>>>(tfB, (float*)tfA, mag, gmax);
    etf_vh<1><<<g, 256, 0, stream>>>(tfA, (float*)d_out, mag, gmax);
}

// Round 11
// 131.353 us; speedup vs baseline: 1.2951x; 1.2951x over previous
//
#include <hip/hip_runtime.h>

#define BB 2
#define HH 1024
#define WW 1024
#define MU 5

// fused-pass tile geometry
#define TH 32
#define TW 64
#define SH (TH + 2 * MU)   // 42 staged rows
#define SCW 80             // staged cols = TW + 16 (8-col halo each side)
#define SMS 83             // em LDS row stride (odd -> conflict-free H reads)
#define SVS 81             // V-result LDS row stride (odd -> conflict-free H reads)

__device__ __forceinline__ float fast_rcp(float x) { return __builtin_amdgcn_rcpf(x); }
__device__ __forceinline__ float fast_rsq(float x) { return __builtin_amdgcn_rsqf(x); }

// ---------------------------------------------------------------------------
// Kernel 1: Sobel + init tangent (interleaved (B,H,W,2)) + raw mag + block max.
// (R7-proven version: no atomics, no fences — R10 lesson.)
// ---------------------------------------------------------------------------
#define SR 8
__global__ __launch_bounds__(256) void sobel_init(
    const float* __restrict__ x,
    float* __restrict__ tf,          // (B,H,W,2) interleaved
    float* __restrict__ mag,         // (B,H,W) raw
    float* __restrict__ block_max)   // 1024
{
    __shared__ float xs[SR + 2][264];
    const int t = threadIdx.x;
    const int w0 = blockIdx.x * 256;
    const int h0 = blockIdx.y * SR;
    const int b = blockIdx.z;
    const size_t plane = (size_t)HH * WW;
    const float* xb = x + (size_t)b * plane;

    for (int i = t; i < (SR + 2) * 66; i += 256) {
        int r = i / 66, c4 = i % 66;
        int g = h0 - 1 + r;
        int gw = w0 - 4 + 4 * c4;
        float4 v = make_float4(0.f, 0.f, 0.f, 0.f);
        if (g >= 0 && g < HH && gw >= 0 && gw < WW)
            v = *(const float4*)(xb + (size_t)g * WW + gw);
        *(float4*)&xs[r][4 * c4] = v;
    }
    __syncthreads();

    float lmax = 0.f;
    const int c = 4 + t;
    #pragma unroll
    for (int k = 0; k < SR; ++k) {
        const float* rT = xs[k], * rM = xs[k + 1], * rB = xs[k + 2];
        float tl = rT[c - 1], tc = rT[c], tr = rT[c + 1];
        float ml = rM[c - 1],             mr = rM[c + 1];
        float bl = rB[c - 1], bc = rB[c], br = rB[c + 1];
        float s0 = (bl - tl) + 2.f * (bc - tc) + (br - tr);   // k
        float s1 = (tr - tl) + 2.f * (mr - ml) + (br - bl);   // k^T
        float m = sqrtf(fmaf(s0, s0, s1 * s1));
        float inv = (m == 0.f) ? 1.f : fast_rcp(m);
        size_t gi = (size_t)(h0 + k) * WW + (w0 + t);
        mag[(size_t)b * plane + gi] = m;
        ((float2*)tf)[(size_t)b * plane + gi] = make_float2(-s1 * inv, s0 * inv);
        lmax = fmaxf(lmax, m);
    }

    #pragma unroll
    for (int off = 32; off; off >>= 1) lmax = fmaxf(lmax, __shfl_down(lmax, off, 64));
    __shared__ float smax[4];
    if ((t & 63) == 0) smax[t >> 6] = lmax;
    __syncthreads();
    if (t == 0)
        block_max[(blockIdx.z * 128 + blockIdx.y) * 4 + blockIdx.x] =
            fmaxf(fmaxf(smax[0], smax[1]), fmaxf(smax[2], smax[3]));
}

// ---------------------------------------------------------------------------
// Kernel 2: FUSED V+H ETF pass (exact R7 structure, proven 131.7us) + inline
// PROLOGUE: every block redundantly reduces block_max[1024] -> gmax (L2-hot,
// ~1us) — removes the reduce_max dispatch + its launch gap entirely.
// Weight identity: (tanh(my-mx)+1)/2 == 1/(1 + em_y/em_x), em=exp(-2*mag/max),
// em computed during staging from RAW mag.
// LDS 40824+16 B -> 4 blocks/CU (163.4KB/CU < 160KiB cap per 4 blocks).
// OOB staging: tang=0, em=1 (exact reference zero-pad; normalize(0)=0).
// ---------------------------------------------------------------------------
template <int PLANAR_OUT>
__global__ __launch_bounds__(256, 4) void etf_vh(
    const float* __restrict__ tin,   // (B,H,W,2) interleaved
    float* __restrict__ tout,        // interleaved, or planar (B,2,H,W)
    const float* __restrict__ mag,   // (B,H,W) RAW
    const float* __restrict__ block_max)
{
    __shared__ float lds[SH * SCW * 2 + SH * SMS];   // 40824 B
    __shared__ float smax[4];
    float* st  = lds;                 // staged tang, float2/px, row stride 160 floats
    float* sm  = lds + SH * SCW * 2;  // staged em, row stride SMS
    float* sv0 = lds;                 // V results plane 0 (aliases st)
    float* sv1 = lds + TH * SVS;      // V results plane 1

    const int t = threadIdx.x;
    const int w0 = blockIdx.x * TW;
    const int h0 = blockIdx.y * TH;
    const int b = blockIdx.z;
    const size_t plane = (size_t)HH * WW;
    const float* tb = tin + 2 * (size_t)b * plane;
    const float* mb = mag + (size_t)b * plane;

    // ---- prologue: redundant gmax reduce (no extra dispatch)
    {
        float m = fmaxf(fmaxf(block_max[t], block_max[t + 256]),
                        fmaxf(block_max[t + 512], block_max[t + 768]));
        #pragma unroll
        for (int off = 32; off; off >>= 1) m = fmaxf(m, __shfl_down(m, off, 64));
        if ((t & 63) == 0) smax[t >> 6] = m;
    }
    __syncthreads();
    const float gm = fmaxf(fmaxf(smax[0], smax[1]), fmaxf(smax[2], smax[3]));
    const float s2 = 2.f * fast_rcp(gm);

    // ---- stage: tang 42x40 float4 (2px) chunks; em 42x20 float4 (4px) + exp
    for (int i = t; i < SH * 40 + SH * 20; i += 256) {
        if (i < SH * 40) {
            int r = i / 40, c4 = i % 40;
            int g = h0 - MU + r;
            int gw = w0 - 8 + 2 * c4;
            float4 v = make_float4(0.f, 0.f, 0.f, 0.f);
            if (g >= 0 && g < HH && gw >= 0 && gw < WW)
                v = *(const float4*)(tb + 2 * ((size_t)g * WW + gw));
            *(float4*)&st[r * (SCW * 2) + 4 * c4] = v;    // 16B-aligned
        } else {
            int j = i - SH * 40;
            int r = j / 20, c4 = j % 20;
            int g = h0 - MU + r;
            int gw = w0 - 8 + 4 * c4;
            float4 v = make_float4(0.f, 0.f, 0.f, 0.f);   // mag=0 -> em=1
            if (g >= 0 && g < HH && gw >= 0 && gw < WW)
                v = *(const float4*)(mb + (size_t)g * WW + gw);
            float* dst = &sm[r * SMS + 4 * c4];
            dst[0] = __expf(-s2 * v.x);
            dst[1] = __expf(-s2 * v.y);
            dst[2] = __expf(-s2 * v.z);
            dst[3] = __expf(-s2 * v.w);
        }
    }
    __syncthreads();

    // ---- shared register window (reused by V then H phase)
    float r0a[21], r1a[21], rea[21];

    // ---- V phase: 240 threads = 80 cols x 3 row-strips {11,11,10}.
    const int c = t % 80;
    const int strip = t / 80;
    const int vr0row = strip * 11;
    const int Rv = (strip == 2) ? 10 : 11;
    if (t < 240) {
        #pragma unroll
        for (int j = 0; j < 21; ++j) {
            if (j < Rv + 10) {
                float2 v = *(const float2*)&st[((vr0row + j) * SCW + c) * 2];
                r0a[j] = v.x; r1a[j] = v.y;
                rea[j] = sm[(vr0row + j) * SMS + c];
            }
        }
    }
    __syncthreads();          // all st reads done; safe to overwrite via sv alias

    if (t < 240) {
        #pragma unroll
        for (int i = 0; i < 11; ++i) {
            if (i < Rv) {
                float tx0 = r0a[i + 5], tx1 = r1a[i + 5];
                float remx = fast_rcp(rea[i + 5]);
                float a0 = 0.f, a1 = 0.f;
                #pragma unroll
                for (int d = 0; d <= 2 * MU; ++d) {
                    float y0 = r0a[i + d], y1 = r1a[i + d], ey = rea[i + d];
                    float s = fast_rcp(fmaf(ey, remx, 1.f));    // (tanh(my-mx)+1)/2
                    float w = s * fmaf(tx0, y0, tx1 * y1);
                    a0 = fmaf(y0, w, a0);
                    a1 = fmaf(y1, w, a1);
                }
                float n2 = fmaf(a0, a0, a1 * a1);
                float inv = (n2 == 0.f) ? 1.f : fast_rsq(n2);
                sv0[(vr0row + i) * SVS + c] = a0 * inv;
                sv1[(vr0row + i) * SVS + c] = a1 * inv;
            }
        }
    }
    __syncthreads();

    // ---- H phase: lane<->row map (r = t&31, colgroup = t>>5 of 8 cols).
    // Reuse r0a/r1a/rea[0..17] as the 18-value window.
    const int r = t & 31;
    const int cg = t >> 5;
    const int cbase = 8 + cg * 8;            // staged col of first center
    #pragma unroll
    for (int j = 0; j < 18; ++j) {
        int sc = cbase - 5 + j;              // 3..76: always in [0,80)
        r0a[j] = sv0[r * SVS + sc];
        r1a[j] = sv1[r * SVS + sc];
        rea[j] = sm[(r + MU) * SMS + sc];
    }
    __syncthreads();          // all sv reads done; safe to overwrite below

    #pragma unroll
    for (int k = 0; k < 8; ++k) {
        float tx0 = r0a[k + 5], tx1 = r1a[k + 5];
        float remx = fast_rcp(rea[k + 5]);
        float a0 = 0.f, a1 = 0.f;
        #pragma unroll
        for (int d = 0; d <= 2 * MU; ++d) {
            float y0 = r0a[k + d], y1 = r1a[k + d], ey = rea[k + d];
            float s = fast_rcp(fmaf(ey, remx, 1.f));
            float w = s * fmaf(tx0, y0, tx1 * y1);
            a0 = fmaf(y0, w, a0);
            a1 = fmaf(y1, w, a1);
        }
        float n2 = fmaf(a0, a0, a1 * a1);
        float inv = (n2 == 0.f) ? 1.f : fast_rsq(n2);
        sv0[r * SVS + cbase + k] = a0 * inv;    // write to LDS (post-barrier)
        sv1[r * SVS + cbase + k] = a1 * inv;
    }
    __syncthreads();

    // ---- coalesced global writeout (lanes along cols — R10 lesson: never
    // let a wave's lanes scatter across rows on global stores)
    #pragma unroll
    for (int m = 0; m < 8; ++m) {
        int px = t + 256 * m;
        int rr = px >> 6, cc = px & 63;
        float v0 = sv0[rr * SVS + 8 + cc];
        float v1 = sv1[rr * SVS + 8 + cc];
        size_t gi = (size_t)(h0 + rr) * WW + (w0 + cc);
        if (PLANAR_OUT) {
            tout[(size_t)(2 * b)     * plane + gi] = v0;
            tout[(size_t)(2 * b + 1) * plane + gi] = v1;
        } else {
            *(float2*)&tout[2 * ((size_t)b * plane + gi)] = make_float2(v0, v1);
        }
    }
}

extern "C" void kernel_launch(void* const* d_in, const int* in_sizes, int n_in,
                              void* d_out, int out_size, void* d_ws, size_t ws_size,
                              hipStream_t stream)
{
    const float* x = (const float*)d_in[0];   // (2,1,1024,1024) fp32
    char* ws = (char*)d_ws;
    const size_t plane = (size_t)HH * WW;

    float* tfA  = (float*)ws;                                           // 16 MB interleaved
    float* tfB  = (float*)(ws + sizeof(float) * BB * 2 * plane);        // 16 MB interleaved
    float* mag  = (float*)(ws + sizeof(float) * BB * 4 * plane);        // 8 MB raw
    float* block_max = (float*)(ws + sizeof(float) * BB * 5 * plane);   // 1024 floats

    sobel_init<<<dim3(4, 128, BB), 256, 0, stream>>>(x, tfA, mag, block_max);

    dim3 g(WW / TW, HH / TH, BB);
    etf_vh<0><<<g, 256, 0, stream>>>(tfA, tfB, mag, block_max);
    etf_vh<0><<<g, 256, 0, stream>>>(tfB, tfA, mag, block_max);
    etf_vh<1><<<g, 256, 0, stream>>>(tfA, (float*)d_out, mag, block_max);
}